// Round 3
// baseline (69.986 us; speedup 1.0000x reference)
//
#include <hip/hip_runtime.h>
#include <math.h>

#define BIG_NEG (-1.0e9f)

constexpr int B = 16, T = 2048, D = 64, C = 32, NF = 16;

typedef float f32x4 __attribute__((ext_vector_type(4)));

// ws layout (floats):
//   [0..63]                 inv_var
//   [64]                    log_norm
//   [96..127]               cc[c] = -0.5*mm[c] + log_norm
//   [128 .. 128+K*C)        length_lp (room up to K=32)
//   [1152 .. 1152+C*D)      wm[c][d] = means[c][d]*inv_var[d]
//   [4096 .. 4096+B*T*C)    emission
//   [.. + B*(T+1)*C)        cs
// total ~ 8.4 MB

// ---------------------------------------------------------------------------
// prep: iv, log_norm, wm, cc, length_lp, trans_lp, init_lp — one block
// ---------------------------------------------------------------------------
__global__ __launch_bounds__(1024) void prep_kernel(
    const float* __restrict__ P,       // (D,NF)
    const float* __restrict__ TL,      // (C,D)
    const float* __restrict__ TR,      // (C,D)
    const float* __restrict__ STD,     // (D,)
    const float* __restrict__ MEANS,   // (C,D)
    const float* __restrict__ PLR,     // (C,)
    const float* __restrict__ LOGITS,  // (C,)
    float* __restrict__ ws,
    float* __restrict__ out_trans,     // (C,C)
    float* __restrict__ out_init,      // (C,)
    int K)
{
    __shared__ float left[C][NF];
    __shared__ float right[C][NF];
    __shared__ float M[C][C + 1];
    __shared__ float lse[C];
    __shared__ float ilse;
    __shared__ float siv[D];
    __shared__ float slogn;

    const int tid = threadIdx.x;

    if (tid < D) {
        float s = STD[tid];
        float v = 1.0f / (s * s);
        siv[tid] = v;
        ws[tid] = v;
    }
    if (tid == 0) {
        float acc = 0.0f;
        for (int d = 0; d < D; ++d) acc += logf(STD[d]);
        float ln = -acc - 58.81206612510332f;  // 0.5*64*log(2*pi)
        slogn = ln;
        ws[64] = ln;
    }
    // left/right projections (C x NF), 512 threads
    if (tid < C * NF) {
        int c = tid >> 4, f = tid & (NF - 1);
        float aL = 0.0f, aR = 0.0f;
        for (int d = 0; d < D; ++d) {
            float p = P[d * NF + f];
            aL = fmaf(TL[c * D + d], p, aL);
            aR = fmaf(TR[c * D + d], p, aR);
        }
        left[c][f] = aL;
        right[c][f] = aR;
    }
    __syncthreads();

    // wm[c][d] = means[c][d] * iv[d]
    for (int i = tid; i < C * D; i += 1024)
        ws[1152 + i] = MEANS[i] * siv[i & 63];

    // cc[c] = -0.5 * sum_d means^2 * iv + log_norm
    if (tid < C) {
        float mm = 0.0f;
        for (int d = 0; d < D; ++d) {
            float m = MEANS[tid * D + d];
            mm = fmaf(m * m, siv[d], mm);
        }
        ws[96 + tid] = -0.5f * mm + slogn;
    }

    // length_lp[k][c] = (k+1)*plr[c] - exp(plr[c]) - lgamma(k+2)
    for (int i = tid; i < K * C; i += 1024) {
        int k = i >> 5, c = i & 31;
        float plr = PLR[c];
        float kk = (float)(k + 1);
        ws[128 + i] = kk * plr - expf(plr) - lgammaf(kk + 1.0f);
    }

    // M[i][j] = sum_f right[i][f] * left[j][f]
    {
        int i = tid >> 5, j = tid & 31;
        float acc = 0.0f;
        for (int f = 0; f < NF; ++f) acc = fmaf(right[i][f], left[j][f], acc);
        M[i][j] = acc;
    }
    __syncthreads();

    if (tid < C) {
        int j = tid;
        float mx = -INFINITY;
        for (int i = 0; i < C; ++i) mx = fmaxf(mx, M[i][j]);
        float s = 0.0f;
        for (int i = 0; i < C; ++i) s += expf(M[i][j] - mx);
        lse[j] = logf(s) + mx;
    }
    if (tid == 32) {
        float mx = -INFINITY;
        for (int i = 0; i < C; ++i) mx = fmaxf(mx, LOGITS[i]);
        float s = 0.0f;
        for (int i = 0; i < C; ++i) s += expf(LOGITS[i] - mx);
        ilse = logf(s) + mx;
    }
    __syncthreads();

    {
        int i = tid >> 5, j = tid & 31;
        out_trans[i * C + j] = M[i][j] - lse[j];
    }
    if (tid < C) out_init[tid] = LOGITS[tid] - ilse;
}

// ---------------------------------------------------------------------------
// emission v2: em[t,c] = xm - 0.5*xx + cc[c]
// block = 32 t x 32 c; thread = 2t x 2c register tile; all operands from
// global (wm/iv/cc are L1-resident, feat block tile 8KB is L1-resident).
// Zero LDS.
// ---------------------------------------------------------------------------
__global__ __launch_bounds__(256) void emission_kernel(
    const float* __restrict__ feat,    // (B*T, D)
    const float* __restrict__ ws,
    float* __restrict__ em)            // (B*T, C)
{
    const float* __restrict__ iv = ws;
    const float* __restrict__ cc = ws + 96;
    const float* __restrict__ wm = ws + 1152;

    const int tid = threadIdx.x;
    const int j = tid & 15;        // c-pair index
    const int i = tid >> 4;        // t-pair index within block
    const size_t t = (size_t)blockIdx.x * 32 + 2 * i;

    const float* f0p = feat + t * D;
    const float* f1p = f0p + D;
    const float* w0p = wm + (2 * j) * D;
    const float* w1p = w0p + D;

    float a00 = 0.f, a01 = 0.f, a10 = 0.f, a11 = 0.f;
    float xx0 = 0.f, xx1 = 0.f;

#pragma unroll
    for (int q = 0; q < 16; ++q) {
        const float4 f0 = *(const float4*)(f0p + 4 * q);
        const float4 f1 = *(const float4*)(f1p + 4 * q);
        const float4 w0 = *(const float4*)(w0p + 4 * q);
        const float4 w1 = *(const float4*)(w1p + 4 * q);
        const float4 v4 = *(const float4*)(iv + 4 * q);

        a00 = fmaf(f0.x, w0.x, a00); a00 = fmaf(f0.y, w0.y, a00);
        a00 = fmaf(f0.z, w0.z, a00); a00 = fmaf(f0.w, w0.w, a00);
        a01 = fmaf(f0.x, w1.x, a01); a01 = fmaf(f0.y, w1.y, a01);
        a01 = fmaf(f0.z, w1.z, a01); a01 = fmaf(f0.w, w1.w, a01);
        a10 = fmaf(f1.x, w0.x, a10); a10 = fmaf(f1.y, w0.y, a10);
        a10 = fmaf(f1.z, w0.z, a10); a10 = fmaf(f1.w, w0.w, a10);
        a11 = fmaf(f1.x, w1.x, a11); a11 = fmaf(f1.y, w1.y, a11);
        a11 = fmaf(f1.z, w1.z, a11); a11 = fmaf(f1.w, w1.w, a11);

        xx0 = fmaf(f0.x * v4.x, f0.x, xx0); xx0 = fmaf(f0.y * v4.y, f0.y, xx0);
        xx0 = fmaf(f0.z * v4.z, f0.z, xx0); xx0 = fmaf(f0.w * v4.w, f0.w, xx0);
        xx1 = fmaf(f1.x * v4.x, f1.x, xx1); xx1 = fmaf(f1.y * v4.y, f1.y, xx1);
        xx1 = fmaf(f1.z * v4.z, f1.z, xx1); xx1 = fmaf(f1.w * v4.w, f1.w, xx1);
    }

    const float c0 = cc[2 * j], c1 = cc[2 * j + 1];
    float2 r0 = make_float2(a00 - 0.5f * xx0 + c0, a01 - 0.5f * xx0 + c1);
    float2 r1 = make_float2(a10 - 0.5f * xx1 + c0, a11 - 0.5f * xx1 + c1);
    *(float2*)(em + t * C + 2 * j) = r0;
    *(float2*)(em + (t + 1) * C + 2 * j) = r1;
}

// ---------------------------------------------------------------------------
// scan: cumsum over T per (b,c); block = (b,c), 256 threads x 8 t each
// ---------------------------------------------------------------------------
__global__ __launch_bounds__(256) void scan_kernel(
    const float* __restrict__ em,      // (B,T,C)
    float* __restrict__ cs)            // (B,T+1,C)
{
    __shared__ float sums[256];
    const int tid = threadIdx.x;
    const int b = blockIdx.x >> 5, c = blockIdx.x & 31;

    const float* ebase = em + ((size_t)b * T) * C + c;
    float loc[8];
    float run = 0.0f;
    const int t0 = tid * 8;
#pragma unroll
    for (int j = 0; j < 8; ++j) {
        run += ebase[(size_t)(t0 + j) * C];
        loc[j] = run;
    }
    sums[tid] = run;
    __syncthreads();
    for (int off = 1; off < 256; off <<= 1) {
        float v = (tid >= off) ? sums[tid - off] : 0.0f;
        __syncthreads();
        sums[tid] += v;
        __syncthreads();
    }
    const float excl = sums[tid] - run;

    float* cbase = cs + ((size_t)b * (T + 1)) * C + c;
    if (tid == 0) cbase[0] = 0.0f;
#pragma unroll
    for (int j = 0; j < 8; ++j)
        cbase[(size_t)(t0 + j + 1) * C] = excl + loc[j];
}

// ---------------------------------------------------------------------------
// span: out[b,k,t,c] = (t>=k ? cs[b,t+1,c]-cs[b,t-k,c] : BIG_NEG) + llp[k,c]
// exact grid, one float4 per thread, magic division, nontemporal stores
// ---------------------------------------------------------------------------
__global__ __launch_bounds__(256) void span_kernel(
    const float* __restrict__ cs,
    const float* __restrict__ llp,
    float* __restrict__ out,
    int K, unsigned kmagic)
{
    const int u = blockIdx.x * 256 + threadIdx.x;
    const int c = (u & 7) << 2;
    const int rest = u >> 3;
    const int t = rest & (T - 1);
    const int bk = rest >> 11;
    const int b = (int)(((unsigned long long)bk * kmagic) >> 24);
    const int k = bk - b * K;

    const float4 lv = *(const float4*)&llp[k * C + c];
    const int start = t - k;
    f32x4 r;
    if (start >= 0) {
        const float4 e = *(const float4*)&cs[((size_t)(b * (T + 1) + t + 1)) * C + c];
        const float4 s = *(const float4*)&cs[((size_t)(b * (T + 1) + start)) * C + c];
        r = (f32x4){e.x - s.x + lv.x, e.y - s.y + lv.y,
                    e.z - s.z + lv.z, e.w - s.w + lv.w};
    } else {
        r = (f32x4){BIG_NEG + lv.x, BIG_NEG + lv.y,
                    BIG_NEG + lv.z, BIG_NEG + lv.w};
    }
    __builtin_nontemporal_store(r, (f32x4*)&out[(size_t)u * 4]);
}

// ---------------------------------------------------------------------------
extern "C" void kernel_launch(void* const* d_in, const int* in_sizes, int n_in,
                              void* d_out, int out_size, void* d_ws, size_t ws_size,
                              hipStream_t stream) {
    const float* feat   = (const float*)d_in[0];
    const float* P      = (const float*)d_in[1];
    const float* TL     = (const float*)d_in[2];
    const float* TR     = (const float*)d_in[3];
    const float* MEANS  = (const float*)d_in[4];
    const float* STDV   = (const float*)d_in[5];
    const float* PLR    = (const float*)d_in[6];
    const float* LOGITS = (const float*)d_in[7];

    const int K = (out_size - (C * C + C)) / (B * T * C);
    const unsigned kmagic = (unsigned)((16777216ull + (unsigned)K - 1) / (unsigned)K);

    float* ws  = (float*)d_ws;
    float* llp = ws + 128;
    float* em  = ws + 4096;
    float* cs  = em + (size_t)B * T * C;

    float* out       = (float*)d_out;
    float* out_trans = out + (size_t)B * K * T * C;
    float* out_init  = out_trans + C * C;

    prep_kernel<<<1, 1024, 0, stream>>>(P, TL, TR, STDV, MEANS, PLR, LOGITS,
                                        ws, out_trans, out_init, K);
    emission_kernel<<<B * T / 32, 256, 0, stream>>>(feat, ws, em);
    scan_kernel<<<B * C, 256, 0, stream>>>(em, cs);

    const int total4 = B * K * T * C / 4;
    span_kernel<<<total4 / 256, 256, 0, stream>>>(cs, llp, out, K, kmagic);
}

// Round 4
// 63.495 us; speedup vs baseline: 1.1022x; 1.1022x over previous
//
#include <hip/hip_runtime.h>
#include <math.h>

#define BIG_NEG (-1.0e9f)

constexpr int B = 16, T = 2048, D = 64, C = 32, NF = 16;

typedef float f32x4 __attribute__((ext_vector_type(4)));

// ws layout (floats):
//   [0..63]                 inv_var
//   [64]                    log_norm
//   [96..127]               cc[c] = -0.5*mm[c] + log_norm
//   [128 .. 128+K*C)        length_lp (room up to K=32)
//   [1152 .. 1152+C*D)      wm[c][d] = means[c][d]*inv_var[d]
//   [4096 .. 4096+B*C*T)    emission, TRANSPOSED layout (b,c,t)
//   [.. + B*(T+1)*C)        cs, layout (b,t,c)
// total ~ 8.4 MB

// ---------------------------------------------------------------------------
// prep: iv, log_norm, wm, cc, length_lp, trans_lp, init_lp — one block
// ---------------------------------------------------------------------------
__global__ __launch_bounds__(1024) void prep_kernel(
    const float* __restrict__ P,       // (D,NF)
    const float* __restrict__ TL,      // (C,D)
    const float* __restrict__ TR,      // (C,D)
    const float* __restrict__ STD,     // (D,)
    const float* __restrict__ MEANS,   // (C,D)
    const float* __restrict__ PLR,     // (C,)
    const float* __restrict__ LOGITS,  // (C,)
    float* __restrict__ ws,
    float* __restrict__ out_trans,     // (C,C)
    float* __restrict__ out_init,      // (C,)
    int K)
{
    __shared__ float left[C][NF];
    __shared__ float right[C][NF];
    __shared__ float M[C][C + 1];
    __shared__ float lse[C];
    __shared__ float ilse;
    __shared__ float siv[D];
    __shared__ float slogn;

    const int tid = threadIdx.x;

    if (tid < D) {
        float s = STD[tid];
        float v = 1.0f / (s * s);
        siv[tid] = v;
        ws[tid] = v;
    }
    if (tid == 0) {
        float acc = 0.0f;
        for (int d = 0; d < D; ++d) acc += logf(STD[d]);
        float ln = -acc - 58.81206612510332f;  // 0.5*64*log(2*pi)
        slogn = ln;
        ws[64] = ln;
    }
    // left/right projections (C x NF), 512 threads
    if (tid < C * NF) {
        int c = tid >> 4, f = tid & (NF - 1);
        float aL = 0.0f, aR = 0.0f;
        for (int d = 0; d < D; ++d) {
            float p = P[d * NF + f];
            aL = fmaf(TL[c * D + d], p, aL);
            aR = fmaf(TR[c * D + d], p, aR);
        }
        left[c][f] = aL;
        right[c][f] = aR;
    }
    __syncthreads();

    // wm[c][d] = means[c][d] * iv[d]
    for (int i = tid; i < C * D; i += 1024)
        ws[1152 + i] = MEANS[i] * siv[i & 63];

    // cc[c] = -0.5 * sum_d means^2 * iv + log_norm
    if (tid < C) {
        float mm = 0.0f;
        for (int d = 0; d < D; ++d) {
            float m = MEANS[tid * D + d];
            mm = fmaf(m * m, siv[d], mm);
        }
        ws[96 + tid] = -0.5f * mm + slogn;
    }

    // length_lp[k][c] = (k+1)*plr[c] - exp(plr[c]) - lgamma(k+2)
    for (int i = tid; i < K * C; i += 1024) {
        int k = i >> 5, c = i & 31;
        float plr = PLR[c];
        float kk = (float)(k + 1);
        ws[128 + i] = kk * plr - expf(plr) - lgammaf(kk + 1.0f);
    }

    // M[i][j] = sum_f right[i][f] * left[j][f]
    {
        int i = tid >> 5, j = tid & 31;
        float acc = 0.0f;
        for (int f = 0; f < NF; ++f) acc = fmaf(right[i][f], left[j][f], acc);
        M[i][j] = acc;
    }
    __syncthreads();

    if (tid < C) {
        int j = tid;
        float mx = -INFINITY;
        for (int i = 0; i < C; ++i) mx = fmaxf(mx, M[i][j]);
        float s = 0.0f;
        for (int i = 0; i < C; ++i) s += expf(M[i][j] - mx);
        lse[j] = logf(s) + mx;
    }
    if (tid == 32) {
        float mx = -INFINITY;
        for (int i = 0; i < C; ++i) mx = fmaxf(mx, LOGITS[i]);
        float s = 0.0f;
        for (int i = 0; i < C; ++i) s += expf(LOGITS[i] - mx);
        ilse = logf(s) + mx;
    }
    __syncthreads();

    {
        int i = tid >> 5, j = tid & 31;
        out_trans[i * C + j] = M[i][j] - lse[j];
    }
    if (tid < C) out_init[tid] = LOGITS[tid] - ilse;
}

// ---------------------------------------------------------------------------
// emission: em_T[b,c,t] = xm - 0.5*xx + cc[c]   (TRANSPOSED output layout)
// block = 32 t x 32 c; thread = 2t x 2c register tile; zero LDS.
// ---------------------------------------------------------------------------
__global__ __launch_bounds__(256) void emission_kernel(
    const float* __restrict__ feat,    // (B*T, D)
    const float* __restrict__ ws,
    float* __restrict__ emT)           // (B, C, T)
{
    const float* __restrict__ iv = ws;
    const float* __restrict__ cc = ws + 96;
    const float* __restrict__ wm = ws + 1152;

    const int tid = threadIdx.x;
    const int j = tid & 15;        // c-pair index
    const int i = tid >> 4;        // t-pair index within block
    const size_t tg = (size_t)blockIdx.x * 32 + 2 * i;

    const float* f0p = feat + tg * D;
    const float* f1p = f0p + D;
    const float* w0p = wm + (2 * j) * D;
    const float* w1p = w0p + D;

    float a00 = 0.f, a01 = 0.f, a10 = 0.f, a11 = 0.f;
    float xx0 = 0.f, xx1 = 0.f;

#pragma unroll
    for (int q = 0; q < 16; ++q) {
        const float4 f0 = *(const float4*)(f0p + 4 * q);
        const float4 f1 = *(const float4*)(f1p + 4 * q);
        const float4 w0 = *(const float4*)(w0p + 4 * q);
        const float4 w1 = *(const float4*)(w1p + 4 * q);
        const float4 v4 = *(const float4*)(iv + 4 * q);

        a00 = fmaf(f0.x, w0.x, a00); a00 = fmaf(f0.y, w0.y, a00);
        a00 = fmaf(f0.z, w0.z, a00); a00 = fmaf(f0.w, w0.w, a00);
        a01 = fmaf(f0.x, w1.x, a01); a01 = fmaf(f0.y, w1.y, a01);
        a01 = fmaf(f0.z, w1.z, a01); a01 = fmaf(f0.w, w1.w, a01);
        a10 = fmaf(f1.x, w0.x, a10); a10 = fmaf(f1.y, w0.y, a10);
        a10 = fmaf(f1.z, w0.z, a10); a10 = fmaf(f1.w, w0.w, a10);
        a11 = fmaf(f1.x, w1.x, a11); a11 = fmaf(f1.y, w1.y, a11);
        a11 = fmaf(f1.z, w1.z, a11); a11 = fmaf(f1.w, w1.w, a11);

        xx0 = fmaf(f0.x * v4.x, f0.x, xx0); xx0 = fmaf(f0.y * v4.y, f0.y, xx0);
        xx0 = fmaf(f0.z * v4.z, f0.z, xx0); xx0 = fmaf(f0.w * v4.w, f0.w, xx0);
        xx1 = fmaf(f1.x * v4.x, f1.x, xx1); xx1 = fmaf(f1.y * v4.y, f1.y, xx1);
        xx1 = fmaf(f1.z * v4.z, f1.z, xx1); xx1 = fmaf(f1.w * v4.w, f1.w, xx1);
    }

    const float c0 = cc[2 * j], c1 = cc[2 * j + 1];
    const int b  = (int)(tg >> 11);
    const int tl = (int)(tg & (T - 1));
    float* p0 = emT + ((size_t)(b * C + 2 * j)) * T + tl;
    float* p1 = p0 + T;
    *(float2*)p0 = make_float2(a00 - 0.5f * xx0 + c0, a10 - 0.5f * xx1 + c0);
    *(float2*)p1 = make_float2(a01 - 0.5f * xx0 + c1, a11 - 0.5f * xx1 + c1);
}

// ---------------------------------------------------------------------------
// scan: cumsum over T per (b,c); block = (b,c); reads em_T contiguously
// (thread tid owns t = tid*8 .. tid*8+7), writes cs in (b,t,c) layout.
// ---------------------------------------------------------------------------
__global__ __launch_bounds__(256) void scan_kernel(
    const float* __restrict__ emT,     // (B,C,T)
    float* __restrict__ cs)            // (B,T+1,C)
{
    __shared__ float sums[256];
    const int tid = threadIdx.x;
    const int b = blockIdx.x >> 5, c = blockIdx.x & 31;

    const float* ebase = emT + ((size_t)(b * C + c)) * T + tid * 8;
    const f32x4 v0 = *(const f32x4*)ebase;
    const f32x4 v1 = *(const f32x4*)(ebase + 4);

    float loc[8];
    float run = 0.0f;
    run += v0.x; loc[0] = run;
    run += v0.y; loc[1] = run;
    run += v0.z; loc[2] = run;
    run += v0.w; loc[3] = run;
    run += v1.x; loc[4] = run;
    run += v1.y; loc[5] = run;
    run += v1.z; loc[6] = run;
    run += v1.w; loc[7] = run;

    sums[tid] = run;
    __syncthreads();
    for (int off = 1; off < 256; off <<= 1) {
        float v = (tid >= off) ? sums[tid - off] : 0.0f;
        __syncthreads();
        sums[tid] += v;
        __syncthreads();
    }
    const float excl = sums[tid] - run;

    const int t0 = tid * 8;
    float* cbase = cs + ((size_t)b * (T + 1)) * C + c;
    if (tid == 0) cbase[0] = 0.0f;
#pragma unroll
    for (int j = 0; j < 8; ++j)
        cbase[(size_t)(t0 + j + 1) * C] = excl + loc[j];
}

// ---------------------------------------------------------------------------
// span v3: thread owns (b, t, c-quad), loops over ALL k.
// out[b,k,t,c] = (t>=k ? cs[b,t+1,c]-cs[b,t-k,c] : BIG_NEG) + llp[k,c]
// e-load hoisted (1 per thread), llp in LDS, K independent stores per thread.
// ---------------------------------------------------------------------------
__global__ __launch_bounds__(256) void span_kernel(
    const float* __restrict__ cs,      // (B,T+1,C)
    const float* __restrict__ llp,     // (K,C)
    float* __restrict__ out,           // (B,K,T,C)
    int K)
{
    __shared__ float sllp[1024];
    const int tid = threadIdx.x;
    for (int i = tid; i < K * C; i += 256) sllp[i] = llp[i];
    __syncthreads();

    const int g = blockIdx.x * 256 + tid;
    const int c = (g & 7) << 2;
    const int t = (g >> 3) & (T - 1);
    const int b = g >> 14;

    const float* csb = cs + (size_t)b * (T + 1) * C + c;
    const f32x4 e = *(const f32x4*)(csb + (size_t)(t + 1) * C);
    float* ob = out + ((size_t)(b * K) * T + t) * C + c;

    for (int k = 0; k < K; ++k) {
        const f32x4 lv = *(const f32x4*)&sllp[k * C + c];
        f32x4 r;
        if (t - k >= 0) {
            const f32x4 s = *(const f32x4*)(csb + (size_t)(t - k) * C);
            r = e - s + lv;
        } else {
            r = BIG_NEG + lv;
        }
        *(f32x4*)(ob + (size_t)k * T * C) = r;
    }
}

// ---------------------------------------------------------------------------
extern "C" void kernel_launch(void* const* d_in, const int* in_sizes, int n_in,
                              void* d_out, int out_size, void* d_ws, size_t ws_size,
                              hipStream_t stream) {
    const float* feat   = (const float*)d_in[0];
    const float* P      = (const float*)d_in[1];
    const float* TL     = (const float*)d_in[2];
    const float* TR     = (const float*)d_in[3];
    const float* MEANS  = (const float*)d_in[4];
    const float* STDV   = (const float*)d_in[5];
    const float* PLR    = (const float*)d_in[6];
    const float* LOGITS = (const float*)d_in[7];

    const int K = (out_size - (C * C + C)) / (B * T * C);

    float* ws  = (float*)d_ws;
    float* llp = ws + 128;
    float* emT = ws + 4096;
    float* cs  = emT + (size_t)B * T * C;

    float* out       = (float*)d_out;
    float* out_trans = out + (size_t)B * K * T * C;
    float* out_init  = out_trans + C * C;

    prep_kernel<<<1, 1024, 0, stream>>>(P, TL, TR, STDV, MEANS, PLR, LOGITS,
                                        ws, out_trans, out_init, K);
    emission_kernel<<<B * T / 32, 256, 0, stream>>>(feat, ws, emT);
    scan_kernel<<<B * C, 256, 0, stream>>>(emT, cs);

    // one thread per (b, t, c-quad); each thread writes all K spans
    span_kernel<<<B * T * (C / 4) / 256, 256, 0, stream>>>(cs, llp, out, K);
}

// Round 5
// 62.483 us; speedup vs baseline: 1.1201x; 1.0162x over previous
//
#include <hip/hip_runtime.h>
#include <math.h>

#define BIG_NEG (-1.0e9f)

constexpr int B = 16, T = 2048, D = 64, C = 32, NF = 16;

typedef float f32x4 __attribute__((ext_vector_type(4)));

// ws layout (floats):
//   [0..63]                 inv_var
//   [64]                    log_norm
//   [96..127]               cc[c] = -0.5*mm[c] + log_norm
//   [128 .. 128+K*C)        length_lp (room up to K=32)
//   [1152 .. 1152+C*D)      wm[c][d] = means[c][d]*inv_var[d]
//   [4096 .. 4096+B*C*T)    emission, TRANSPOSED layout (b,c,t)
//   [.. + B*(T+1)*C)        cs, layout (b,t,c)
// total ~ 8.4 MB

// ---------------------------------------------------------------------------
// prep: iv, log_norm, wm, cc, length_lp, trans_lp, init_lp — one block
// ---------------------------------------------------------------------------
__global__ __launch_bounds__(1024) void prep_kernel(
    const float* __restrict__ P,       // (D,NF)
    const float* __restrict__ TL,      // (C,D)
    const float* __restrict__ TR,      // (C,D)
    const float* __restrict__ STD,     // (D,)
    const float* __restrict__ MEANS,   // (C,D)
    const float* __restrict__ PLR,     // (C,)
    const float* __restrict__ LOGITS,  // (C,)
    float* __restrict__ ws,
    float* __restrict__ out_trans,     // (C,C)
    float* __restrict__ out_init,      // (C,)
    int K)
{
    __shared__ float left[C][NF];
    __shared__ float right[C][NF];
    __shared__ float M[C][C + 1];
    __shared__ float lse[C];
    __shared__ float ilse;
    __shared__ float siv[D];
    __shared__ float red[D];
    __shared__ float slogn;

    const int tid = threadIdx.x;

    // ---- phase 0: independent loads/transforms ----
    if (tid < D) {
        float s = STD[tid];
        float v = 1.0f / (s * s);
        siv[tid] = v;
        ws[tid] = v;
        red[tid] = logf(s);
    }
    // left/right projections (C x NF), 512 threads
    if (tid < C * NF) {
        int c = tid >> 4, f = tid & (NF - 1);
        float aL = 0.0f, aR = 0.0f;
        for (int d = 0; d < D; ++d) {
            float p = P[d * NF + f];
            aL = fmaf(TL[c * D + d], p, aL);
            aR = fmaf(TR[c * D + d], p, aR);
        }
        left[c][f] = aL;
        right[c][f] = aR;
    }
    // length_lp[k][c] = (k+1)*plr[c] - exp(plr[c]) - lgamma(k+2)
    for (int i = tid; i < K * C; i += 1024) {
        int k = i >> 5, c = i & 31;
        float plr = PLR[c];
        float kk = (float)(k + 1);
        ws[128 + i] = kk * plr - expf(plr) - lgammaf(kk + 1.0f);
    }
    __syncthreads();

    // ---- phase 1: uses siv / left / right ----
    if (tid == 0) {
        float acc = 0.0f;
        for (int d = 0; d < D; ++d) acc += red[d];
        float ln = -acc - 58.81206612510332f;  // 0.5*64*log(2*pi)
        slogn = ln;
        ws[64] = ln;
    }
    // wm[c][d] = means[c][d] * iv[d]
    for (int i = tid; i < C * D; i += 1024)
        ws[1152 + i] = MEANS[i] * siv[i & 63];

    // M[i][j] = sum_f right[i][f] * left[j][f]
    {
        int i = tid >> 5, j = tid & 31;
        float acc = 0.0f;
        for (int f = 0; f < NF; ++f) acc = fmaf(right[i][f], left[j][f], acc);
        M[i][j] = acc;
    }
    __syncthreads();

    // ---- phase 2: uses M / slogn ----
    // cc[c] = -0.5 * sum_d means^2 * iv + log_norm
    if (tid >= 64 && tid < 64 + C) {
        int c = tid - 64;
        float mm = 0.0f;
        for (int d = 0; d < D; ++d) {
            float m = MEANS[c * D + d];
            mm = fmaf(m * m, siv[d], mm);
        }
        ws[96 + c] = -0.5f * mm + slogn;
    }
    if (tid < C) {
        int j = tid;
        float mx = -INFINITY;
        for (int i = 0; i < C; ++i) mx = fmaxf(mx, M[i][j]);
        float s = 0.0f;
        for (int i = 0; i < C; ++i) s += expf(M[i][j] - mx);
        lse[j] = logf(s) + mx;
    }
    if (tid == 32) {
        float mx = -INFINITY;
        for (int i = 0; i < C; ++i) mx = fmaxf(mx, LOGITS[i]);
        float s = 0.0f;
        for (int i = 0; i < C; ++i) s += expf(LOGITS[i] - mx);
        ilse = logf(s) + mx;
    }
    __syncthreads();

    {
        int i = tid >> 5, j = tid & 31;
        out_trans[i * C + j] = M[i][j] - lse[j];
    }
    if (tid < C) out_init[tid] = LOGITS[tid] - ilse;
}

// ---------------------------------------------------------------------------
// emission: em_T[b,c,t] = xm - 0.5*xx + cc[c]   (TRANSPOSED output layout)
// block = 32 t x 32 c; thread = 2t x 2c register tile; zero LDS.
// ---------------------------------------------------------------------------
__global__ __launch_bounds__(256) void emission_kernel(
    const float* __restrict__ feat,    // (B*T, D)
    const float* __restrict__ ws,
    float* __restrict__ emT)           // (B, C, T)
{
    const float* __restrict__ iv = ws;
    const float* __restrict__ cc = ws + 96;
    const float* __restrict__ wm = ws + 1152;

    const int tid = threadIdx.x;
    const int j = tid & 15;        // c-pair index
    const int i = tid >> 4;        // t-pair index within block
    const size_t tg = (size_t)blockIdx.x * 32 + 2 * i;

    const float* f0p = feat + tg * D;
    const float* f1p = f0p + D;
    const float* w0p = wm + (2 * j) * D;
    const float* w1p = w0p + D;

    float a00 = 0.f, a01 = 0.f, a10 = 0.f, a11 = 0.f;
    float xx0 = 0.f, xx1 = 0.f;

#pragma unroll
    for (int q = 0; q < 16; ++q) {
        const float4 f0 = *(const float4*)(f0p + 4 * q);
        const float4 f1 = *(const float4*)(f1p + 4 * q);
        const float4 w0 = *(const float4*)(w0p + 4 * q);
        const float4 w1 = *(const float4*)(w1p + 4 * q);
        const float4 v4 = *(const float4*)(iv + 4 * q);

        a00 = fmaf(f0.x, w0.x, a00); a00 = fmaf(f0.y, w0.y, a00);
        a00 = fmaf(f0.z, w0.z, a00); a00 = fmaf(f0.w, w0.w, a00);
        a01 = fmaf(f0.x, w1.x, a01); a01 = fmaf(f0.y, w1.y, a01);
        a01 = fmaf(f0.z, w1.z, a01); a01 = fmaf(f0.w, w1.w, a01);
        a10 = fmaf(f1.x, w0.x, a10); a10 = fmaf(f1.y, w0.y, a10);
        a10 = fmaf(f1.z, w0.z, a10); a10 = fmaf(f1.w, w0.w, a10);
        a11 = fmaf(f1.x, w1.x, a11); a11 = fmaf(f1.y, w1.y, a11);
        a11 = fmaf(f1.z, w1.z, a11); a11 = fmaf(f1.w, w1.w, a11);

        xx0 = fmaf(f0.x * v4.x, f0.x, xx0); xx0 = fmaf(f0.y * v4.y, f0.y, xx0);
        xx0 = fmaf(f0.z * v4.z, f0.z, xx0); xx0 = fmaf(f0.w * v4.w, f0.w, xx0);
        xx1 = fmaf(f1.x * v4.x, f1.x, xx1); xx1 = fmaf(f1.y * v4.y, f1.y, xx1);
        xx1 = fmaf(f1.z * v4.z, f1.z, xx1); xx1 = fmaf(f1.w * v4.w, f1.w, xx1);
    }

    const float c0 = cc[2 * j], c1 = cc[2 * j + 1];
    const int b  = (int)(tg >> 11);
    const int tl = (int)(tg & (T - 1));
    float* p0 = emT + ((size_t)(b * C + 2 * j)) * T + tl;
    float* p1 = p0 + T;
    *(float2*)p0 = make_float2(a00 - 0.5f * xx0 + c0, a10 - 0.5f * xx1 + c0);
    *(float2*)p1 = make_float2(a01 - 0.5f * xx0 + c1, a11 - 0.5f * xx1 + c1);
}

// ---------------------------------------------------------------------------
// scan: cumsum over T per (b,c); block = (b,c); reads em_T contiguously
// (thread tid owns t = tid*8 .. tid*8+7), writes cs in (b,t,c) layout.
// ---------------------------------------------------------------------------
__global__ __launch_bounds__(256) void scan_kernel(
    const float* __restrict__ emT,     // (B,C,T)
    float* __restrict__ cs)            // (B,T+1,C)
{
    __shared__ float sums[256];
    const int tid = threadIdx.x;
    const int b = blockIdx.x >> 5, c = blockIdx.x & 31;

    const float* ebase = emT + ((size_t)(b * C + c)) * T + tid * 8;
    const f32x4 v0 = *(const f32x4*)ebase;
    const f32x4 v1 = *(const f32x4*)(ebase + 4);

    float loc[8];
    float run = 0.0f;
    run += v0.x; loc[0] = run;
    run += v0.y; loc[1] = run;
    run += v0.z; loc[2] = run;
    run += v0.w; loc[3] = run;
    run += v1.x; loc[4] = run;
    run += v1.y; loc[5] = run;
    run += v1.z; loc[6] = run;
    run += v1.w; loc[7] = run;

    sums[tid] = run;
    __syncthreads();
    for (int off = 1; off < 256; off <<= 1) {
        float v = (tid >= off) ? sums[tid - off] : 0.0f;
        __syncthreads();
        sums[tid] += v;
        __syncthreads();
    }
    const float excl = sums[tid] - run;

    const int t0 = tid * 8;
    float* cbase = cs + ((size_t)b * (T + 1)) * C + c;
    if (tid == 0) cbase[0] = 0.0f;
#pragma unroll
    for (int j = 0; j < 8; ++j)
        cbase[(size_t)(t0 + j + 1) * C] = excl + loc[j];
}

// ---------------------------------------------------------------------------
// span v4: thread owns (b, t, c-quad); K is a COMPILE-TIME template param so
// all K s-loads unroll and issue back-to-back (deep vmcnt pipeline), then K
// independent stores stream at write BW. s[] is statically indexed -> VGPRs.
// ---------------------------------------------------------------------------
template<int KT>
__global__ __launch_bounds__(256) void span_kernel_t(
    const float* __restrict__ cs,      // (B,T+1,C)
    const float* __restrict__ llp,     // (K,C)
    float* __restrict__ out)           // (B,KT,T,C)
{
    __shared__ float sllp[KT * C];
    const int tid = threadIdx.x;
    for (int i = tid; i < KT * C; i += 256) sllp[i] = llp[i];
    __syncthreads();

    const int g = blockIdx.x * 256 + tid;
    const int c = (g & 7) << 2;
    const int t = (g >> 3) & (T - 1);
    const int b = g >> 14;

    const float* csb = cs + (size_t)b * (T + 1) * C + c;
    const f32x4 e = *(const f32x4*)(csb + (size_t)(t + 1) * C);

    f32x4 s[KT];
#pragma unroll
    for (int k = 0; k < KT; ++k) {
        int tk = t - k;
        if (tk < 0) tk = 0;
        s[k] = *(const f32x4*)(csb + (size_t)tk * C);
    }

    float* ob = out + ((size_t)(b * KT) * T + t) * C + c;
#pragma unroll
    for (int k = 0; k < KT; ++k) {
        const f32x4 lv = *(const f32x4*)&sllp[k * C + c];
        f32x4 r = e - s[k] + lv;
        if (t < k) r = BIG_NEG + lv;
        *(f32x4*)(ob + (size_t)k * T * C) = r;
    }
}

// runtime-K fallback (not used for K==20)
__global__ __launch_bounds__(256) void span_kernel_rt(
    const float* __restrict__ cs,
    const float* __restrict__ llp,
    float* __restrict__ out,
    int K)
{
    __shared__ float sllp[1024];
    const int tid = threadIdx.x;
    for (int i = tid; i < K * C; i += 256) sllp[i] = llp[i];
    __syncthreads();

    const int g = blockIdx.x * 256 + tid;
    const int c = (g & 7) << 2;
    const int t = (g >> 3) & (T - 1);
    const int b = g >> 14;

    const float* csb = cs + (size_t)b * (T + 1) * C + c;
    const f32x4 e = *(const f32x4*)(csb + (size_t)(t + 1) * C);
    float* ob = out + ((size_t)(b * K) * T + t) * C + c;

    for (int k = 0; k < K; ++k) {
        const f32x4 lv = *(const f32x4*)&sllp[k * C + c];
        f32x4 r;
        if (t - k >= 0) {
            const f32x4 s = *(const f32x4*)(csb + (size_t)(t - k) * C);
            r = e - s + lv;
        } else {
            r = BIG_NEG + lv;
        }
        *(f32x4*)(ob + (size_t)k * T * C) = r;
    }
}

// ---------------------------------------------------------------------------
extern "C" void kernel_launch(void* const* d_in, const int* in_sizes, int n_in,
                              void* d_out, int out_size, void* d_ws, size_t ws_size,
                              hipStream_t stream) {
    const float* feat   = (const float*)d_in[0];
    const float* P      = (const float*)d_in[1];
    const float* TL     = (const float*)d_in[2];
    const float* TR     = (const float*)d_in[3];
    const float* MEANS  = (const float*)d_in[4];
    const float* STDV   = (const float*)d_in[5];
    const float* PLR    = (const float*)d_in[6];
    const float* LOGITS = (const float*)d_in[7];

    const int K = (out_size - (C * C + C)) / (B * T * C);

    float* ws  = (float*)d_ws;
    float* llp = ws + 128;
    float* emT = ws + 4096;
    float* cs  = emT + (size_t)B * T * C;

    float* out       = (float*)d_out;
    float* out_trans = out + (size_t)B * K * T * C;
    float* out_init  = out_trans + C * C;

    prep_kernel<<<1, 1024, 0, stream>>>(P, TL, TR, STDV, MEANS, PLR, LOGITS,
                                        ws, out_trans, out_init, K);
    emission_kernel<<<B * T / 32, 256, 0, stream>>>(feat, ws, emT);
    scan_kernel<<<B * C, 256, 0, stream>>>(emT, cs);

    const int nblk = B * T * (C / 4) / 256;   // 1024
    if (K == 20) {
        span_kernel_t<20><<<nblk, 256, 0, stream>>>(cs, llp, out);
    } else if (K == 16) {
        span_kernel_t<16><<<nblk, 256, 0, stream>>>(cs, llp, out);
    } else if (K == 24) {
        span_kernel_t<24><<<nblk, 256, 0, stream>>>(cs, llp, out);
    } else {
        span_kernel_rt<<<nblk, 256, 0, stream>>>(cs, llp, out, K);
    }
}

// Round 6
// 55.876 us; speedup vs baseline: 1.2525x; 1.1182x over previous
//
#include <hip/hip_runtime.h>
#include <math.h>

#define BIG_NEG (-1.0e9f)

constexpr int B = 16, T = 2048, D = 64, C = 32, NF = 16;

typedef float f32x4 __attribute__((ext_vector_type(4)));

// ws layout (floats):
//   [0..63]                 inv_var
//   [64]                    log_norm
//   [96..127]               cc[c] = -0.5*mm[c] + log_norm
//   [128 .. 128+K*C)        length_lp (room up to K=32)
//   [1152 .. 1152+C*D)      wm[c][d] = means[c][d]*inv_var[d]
//   [4096 .. 4096+B*C*T)    emission, TRANSPOSED layout (b,c,t)
//   [.. + B*(T+1)*C)        cs, layout (b,t,c)

// ---------------------------------------------------------------------------
// prep: iv, log_norm, wm, cc, length_lp, trans_lp, init_lp — one block
// ---------------------------------------------------------------------------
__global__ __launch_bounds__(1024) void prep_kernel(
    const float* __restrict__ P,       // (D,NF)
    const float* __restrict__ TL,      // (C,D)
    const float* __restrict__ TR,      // (C,D)
    const float* __restrict__ STD,     // (D,)
    const float* __restrict__ MEANS,   // (C,D)
    const float* __restrict__ PLR,     // (C,)
    const float* __restrict__ LOGITS,  // (C,)
    float* __restrict__ ws,
    float* __restrict__ out_trans,     // (C,C)
    float* __restrict__ out_init,      // (C,)
    int K)
{
    __shared__ float left[C][NF];
    __shared__ float right[C][NF];
    __shared__ float M[C][C + 1];
    __shared__ float lse[C];
    __shared__ float ilse;
    __shared__ float siv[D];
    __shared__ float red[D];
    __shared__ float slogn;

    const int tid = threadIdx.x;

    // ---- phase 0: independent loads/transforms ----
    if (tid < D) {
        float s = STD[tid];
        float v = 1.0f / (s * s);
        siv[tid] = v;
        ws[tid] = v;
        red[tid] = logf(s);
    }
    if (tid < C * NF) {
        int c = tid >> 4, f = tid & (NF - 1);
        float aL = 0.0f, aR = 0.0f;
        for (int d = 0; d < D; ++d) {
            float p = P[d * NF + f];
            aL = fmaf(TL[c * D + d], p, aL);
            aR = fmaf(TR[c * D + d], p, aR);
        }
        left[c][f] = aL;
        right[c][f] = aR;
    }
    for (int i = tid; i < K * C; i += 1024) {
        int k = i >> 5, c = i & 31;
        float plr = PLR[c];
        float kk = (float)(k + 1);
        ws[128 + i] = kk * plr - expf(plr) - lgammaf(kk + 1.0f);
    }
    __syncthreads();

    // ---- phase 1 ----
    if (tid == 0) {
        float acc = 0.0f;
        for (int d = 0; d < D; ++d) acc += red[d];
        float ln = -acc - 58.81206612510332f;  // 0.5*64*log(2*pi)
        slogn = ln;
        ws[64] = ln;
    }
    for (int i = tid; i < C * D; i += 1024)
        ws[1152 + i] = MEANS[i] * siv[i & 63];

    {
        int i = tid >> 5, j = tid & 31;
        float acc = 0.0f;
        for (int f = 0; f < NF; ++f) acc = fmaf(right[i][f], left[j][f], acc);
        M[i][j] = acc;
    }
    __syncthreads();

    // ---- phase 2 ----
    if (tid >= 64 && tid < 64 + C) {
        int c = tid - 64;
        float mm = 0.0f;
        for (int d = 0; d < D; ++d) {
            float m = MEANS[c * D + d];
            mm = fmaf(m * m, siv[d], mm);
        }
        ws[96 + c] = -0.5f * mm + slogn;
    }
    if (tid < C) {
        int j = tid;
        float mx = -INFINITY;
        for (int i = 0; i < C; ++i) mx = fmaxf(mx, M[i][j]);
        float s = 0.0f;
        for (int i = 0; i < C; ++i) s += expf(M[i][j] - mx);
        lse[j] = logf(s) + mx;
    }
    if (tid == 32) {
        float mx = -INFINITY;
        for (int i = 0; i < C; ++i) mx = fmaxf(mx, LOGITS[i]);
        float s = 0.0f;
        for (int i = 0; i < C; ++i) s += expf(LOGITS[i] - mx);
        ilse = logf(s) + mx;
    }
    __syncthreads();

    {
        int i = tid >> 5, j = tid & 31;
        out_trans[i * C + j] = M[i][j] - lse[j];
    }
    if (tid < C) out_init[tid] = LOGITS[tid] - ilse;
}

// ---------------------------------------------------------------------------
// emission: em_T[b,c,t] = xm - 0.5*xx + cc[c]
// grid remapped for b->XCD affinity: blockIdx = tc*16 + b  (XCD = b%8)
// ---------------------------------------------------------------------------
__global__ __launch_bounds__(256) void emission_kernel(
    const float* __restrict__ feat,    // (B*T, D)
    const float* __restrict__ ws,
    float* __restrict__ emT)           // (B, C, T)
{
    const float* __restrict__ iv = ws;
    const float* __restrict__ cc = ws + 96;
    const float* __restrict__ wm = ws + 1152;

    const int tid = threadIdx.x;
    const int b  = blockIdx.x & 15;
    const int tc = blockIdx.x >> 4;
    const int j = tid & 15;        // c-pair index
    const int i = tid >> 4;        // t-pair index within block
    const int tl = tc * 32 + 2 * i;
    const size_t tg = (size_t)b * T + tl;

    const float* f0p = feat + tg * D;
    const float* f1p = f0p + D;
    const float* w0p = wm + (2 * j) * D;
    const float* w1p = w0p + D;

    float a00 = 0.f, a01 = 0.f, a10 = 0.f, a11 = 0.f;
    float xx0 = 0.f, xx1 = 0.f;

#pragma unroll
    for (int q = 0; q < 16; ++q) {
        const float4 f0 = *(const float4*)(f0p + 4 * q);
        const float4 f1 = *(const float4*)(f1p + 4 * q);
        const float4 w0 = *(const float4*)(w0p + 4 * q);
        const float4 w1 = *(const float4*)(w1p + 4 * q);
        const float4 v4 = *(const float4*)(iv + 4 * q);

        a00 = fmaf(f0.x, w0.x, a00); a00 = fmaf(f0.y, w0.y, a00);
        a00 = fmaf(f0.z, w0.z, a00); a00 = fmaf(f0.w, w0.w, a00);
        a01 = fmaf(f0.x, w1.x, a01); a01 = fmaf(f0.y, w1.y, a01);
        a01 = fmaf(f0.z, w1.z, a01); a01 = fmaf(f0.w, w1.w, a01);
        a10 = fmaf(f1.x, w0.x, a10); a10 = fmaf(f1.y, w0.y, a10);
        a10 = fmaf(f1.z, w0.z, a10); a10 = fmaf(f1.w, w0.w, a10);
        a11 = fmaf(f1.x, w1.x, a11); a11 = fmaf(f1.y, w1.y, a11);
        a11 = fmaf(f1.z, w1.z, a11); a11 = fmaf(f1.w, w1.w, a11);

        xx0 = fmaf(f0.x * v4.x, f0.x, xx0); xx0 = fmaf(f0.y * v4.y, f0.y, xx0);
        xx0 = fmaf(f0.z * v4.z, f0.z, xx0); xx0 = fmaf(f0.w * v4.w, f0.w, xx0);
        xx1 = fmaf(f1.x * v4.x, f1.x, xx1); xx1 = fmaf(f1.y * v4.y, f1.y, xx1);
        xx1 = fmaf(f1.z * v4.z, f1.z, xx1); xx1 = fmaf(f1.w * v4.w, f1.w, xx1);
    }

    const float c0 = cc[2 * j], c1 = cc[2 * j + 1];
    float* p0 = emT + ((size_t)(b * C + 2 * j)) * T + tl;
    float* p1 = p0 + T;
    *(float2*)p0 = make_float2(a00 - 0.5f * xx0 + c0, a10 - 0.5f * xx1 + c0);
    *(float2*)p1 = make_float2(a01 - 0.5f * xx0 + c1, a11 - 0.5f * xx1 + c1);
}

// ---------------------------------------------------------------------------
// scan: cumsum over T per (b,c); grid remapped: blockIdx = c*16 + b (XCD=b%8)
// wave64 shuffle scan, single barrier.
// ---------------------------------------------------------------------------
__global__ __launch_bounds__(256) void scan_kernel(
    const float* __restrict__ emT,     // (B,C,T)
    float* __restrict__ cs)            // (B,T+1,C)
{
    __shared__ float wsum[4];
    const int tid = threadIdx.x;
    const int b = blockIdx.x & 15, c = blockIdx.x >> 4;
    const int lane = tid & 63, wid = tid >> 6;

    const float* ebase = emT + ((size_t)(b * C + c)) * T + tid * 8;
    const f32x4 v0 = *(const f32x4*)ebase;
    const f32x4 v1 = *(const f32x4*)(ebase + 4);

    float loc[8];
    float run = 0.0f;
    run += v0.x; loc[0] = run;
    run += v0.y; loc[1] = run;
    run += v0.z; loc[2] = run;
    run += v0.w; loc[3] = run;
    run += v1.x; loc[4] = run;
    run += v1.y; loc[5] = run;
    run += v1.z; loc[6] = run;
    run += v1.w; loc[7] = run;

    // wave64 inclusive scan of per-thread totals
    float sc = run;
#pragma unroll
    for (int off = 1; off < 64; off <<= 1) {
        float v = __shfl_up(sc, off, 64);
        if (lane >= off) sc += v;
    }
    if (lane == 63) wsum[wid] = sc;
    __syncthreads();
    float wpre = 0.0f;
#pragma unroll
    for (int w = 0; w < 3; ++w)
        wpre += (w < wid) ? wsum[w] : 0.0f;

    const float excl = wpre + sc - run;

    const int t0 = tid * 8;
    float* cbase = cs + ((size_t)b * (T + 1)) * C + c;
    if (tid == 0) cbase[0] = 0.0f;
#pragma unroll
    for (int j = 0; j < 8; ++j)
        cbase[(size_t)(t0 + j + 1) * C] = excl + loc[j];
}

// ---------------------------------------------------------------------------
// span v5: k-OUTER blocks. block = (b, k, t-chunk of 256) writes ONE
// contiguous 32 KB region of out. blockIdx = ((k*8+chunk)*16 + b) so
// XCD = b%8 matches scan's placement of cs[b] (L2-local reads).
// ---------------------------------------------------------------------------
template<int KT>
__global__ __launch_bounds__(256) void span_kernel_t(
    const float* __restrict__ cs,      // (B,T+1,C)
    const float* __restrict__ llp,     // (K,C)
    float* __restrict__ out)           // (B,KT,T,C)
{
    const int tid = threadIdx.x;
    const int b = blockIdx.x & 15;
    const int kc = blockIdx.x >> 4;
    const int k = kc >> 3;
    const int t0 = (kc & 7) << 8;      // chunk*256

    const int c = (tid & 7) << 2;
    const int tb = tid >> 3;           // t_loc = m*32 + tb

    const float* csb = cs + (size_t)b * (T + 1) * C + c;
    const f32x4 lv = *(const f32x4*)&llp[k * C + c];
    float* ob = out + ((size_t)(b * KT + k) * T + t0) * C + c;

#pragma unroll
    for (int m = 0; m < 8; ++m) {
        const int t = t0 + m * 32 + tb;
        const int tk = t - k;
        const f32x4 e = *(const f32x4*)(csb + (size_t)(t + 1) * C);
        const f32x4 s = *(const f32x4*)(csb + (size_t)(tk < 0 ? 0 : tk) * C);
        f32x4 r = e - s + lv;
        if (tk < 0) r = BIG_NEG + lv;
        *(f32x4*)(ob + (size_t)(m * 32 + tb) * C) = r;
    }
}

// runtime-K fallback
__global__ __launch_bounds__(256) void span_kernel_rt(
    const float* __restrict__ cs,
    const float* __restrict__ llp,
    float* __restrict__ out,
    int K)
{
    const int tid = threadIdx.x;
    const int b = blockIdx.x & 15;
    const int kc = blockIdx.x >> 4;
    const int k = kc >> 3;
    const int t0 = (kc & 7) << 8;

    const int c = (tid & 7) << 2;
    const int tb = tid >> 3;

    const float* csb = cs + (size_t)b * (T + 1) * C + c;
    const f32x4 lv = *(const f32x4*)&llp[k * C + c];
    float* ob = out + ((size_t)(b * K + k) * T + t0) * C + c;

#pragma unroll
    for (int m = 0; m < 8; ++m) {
        const int t = t0 + m * 32 + tb;
        const int tk = t - k;
        const f32x4 e = *(const f32x4*)(csb + (size_t)(t + 1) * C);
        const f32x4 s = *(const f32x4*)(csb + (size_t)(tk < 0 ? 0 : tk) * C);
        f32x4 r = e - s + lv;
        if (tk < 0) r = BIG_NEG + lv;
        *(f32x4*)(ob + (size_t)(m * 32 + tb) * C) = r;
    }
}

// ---------------------------------------------------------------------------
extern "C" void kernel_launch(void* const* d_in, const int* in_sizes, int n_in,
                              void* d_out, int out_size, void* d_ws, size_t ws_size,
                              hipStream_t stream) {
    const float* feat   = (const float*)d_in[0];
    const float* P      = (const float*)d_in[1];
    const float* TL     = (const float*)d_in[2];
    const float* TR     = (const float*)d_in[3];
    const float* MEANS  = (const float*)d_in[4];
    const float* STDV   = (const float*)d_in[5];
    const float* PLR    = (const float*)d_in[6];
    const float* LOGITS = (const float*)d_in[7];

    const int K = (out_size - (C * C + C)) / (B * T * C);

    float* ws  = (float*)d_ws;
    float* llp = ws + 128;
    float* emT = ws + 4096;
    float* cs  = emT + (size_t)B * T * C;

    float* out       = (float*)d_out;
    float* out_trans = out + (size_t)B * K * T * C;
    float* out_init  = out_trans + C * C;

    prep_kernel<<<1, 1024, 0, stream>>>(P, TL, TR, STDV, MEANS, PLR, LOGITS,
                                        ws, out_trans, out_init, K);
    emission_kernel<<<B * T / 32, 256, 0, stream>>>(feat, ws, emT);
    scan_kernel<<<B * C, 256, 0, stream>>>(emT, cs);

    const int nblk = B * K * 8;        // (b, k, 8 chunks)
    if (K == 20) {
        span_kernel_t<20><<<nblk, 256, 0, stream>>>(cs, llp, out);
    } else if (K == 16) {
        span_kernel_t<16><<<nblk, 256, 0, stream>>>(cs, llp, out);
    } else if (K == 24) {
        span_kernel_t<24><<<nblk, 256, 0, stream>>>(cs, llp, out);
    } else {
        span_kernel_rt<<<nblk, 256, 0, stream>>>(cs, llp, out, K);
    }
}